// Round 3
// baseline (333.047 us; speedup 1.0000x reference)
//
#include <hip/hip_runtime.h>
#include <math.h>

#define NB 1024
#define NL 196
#define NA 1024
#define NH 1024

typedef __attribute__((ext_vector_type(8))) short bf16x8;
typedef __attribute__((ext_vector_type(4))) float f32x4;

// ws layout (floats)
#define HATT_OFF  0                       // [NB][NA]            4 MB
#define SPART_OFF (NB * NA)               // [NB][NL][2]         1.6 MB
#define CPART_OFF (NB * NA + NB * NL * 2) // [2][NB][NA]         8 MB

// f32 -> bf16 round-to-nearest-even, returned as raw bits
__device__ inline short f2bf(float x) {
    unsigned int u = __float_as_uint(x);
    u += 0x7FFFu + ((u >> 16) & 1u);
    return (short)(u >> 16);
}

// ---------------------------------------------------------------------------
// Kernel 1: h_att[b,a] = sum_k h_prev[b,k] * W_h[a,k] + b_h[a]   (bf16 MFMA)
// ---------------------------------------------------------------------------
__global__ __launch_bounds__(256) void hatt_gemm_mfma(
    const float* __restrict__ hp,   // [NB, NH]
    const float* __restrict__ Wh,   // [NA, NH]
    const float* __restrict__ bh,   // [NA]
    float* __restrict__ hatt)       // [NB, NA] (ws)
{
    __shared__ short As[64][40];
    __shared__ short Ws[64][40];

    const int t   = threadIdx.x;
    const int row = t >> 2;          // 0..63
    const int c8  = (t & 3) << 3;    // 0,8,16,24
    const int brow = blockIdx.y << 6;
    const int bcol = blockIdx.x << 6;

    const float* Ap = hp + (size_t)(brow + row) * NH + c8;
    const float* Wp = Wh + (size_t)(bcol + row) * NH + c8;

    float4 a0 = *(const float4*)(Ap);
    float4 a1 = *(const float4*)(Ap + 4);
    float4 w0 = *(const float4*)(Wp);
    float4 w1 = *(const float4*)(Wp + 4);

    const int lane = t & 63;
    const int wid  = t >> 6;
    const int wr   = (wid >> 1) << 5;
    const int wc   = (wid & 1) << 5;
    const int l15  = lane & 15;
    const int kof  = (lane >> 4) << 3;

    f32x4 acc00 = {}, acc01 = {}, acc10 = {}, acc11 = {};

    for (int kt = 0; kt < NH / 32; ++kt) {
        bf16x8 pa, pb;
        pa[0]=f2bf(a0.x); pa[1]=f2bf(a0.y); pa[2]=f2bf(a0.z); pa[3]=f2bf(a0.w);
        pa[4]=f2bf(a1.x); pa[5]=f2bf(a1.y); pa[6]=f2bf(a1.z); pa[7]=f2bf(a1.w);
        pb[0]=f2bf(w0.x); pb[1]=f2bf(w0.y); pb[2]=f2bf(w0.z); pb[3]=f2bf(w0.w);
        pb[4]=f2bf(w1.x); pb[5]=f2bf(w1.y); pb[6]=f2bf(w1.z); pb[7]=f2bf(w1.w);
        *(bf16x8*)&As[row][c8] = pa;
        *(bf16x8*)&Ws[row][c8] = pb;
        __syncthreads();

        if (kt + 1 < NH / 32) {
            const float* Ap2 = Ap + (kt + 1) * 32;
            const float* Wp2 = Wp + (kt + 1) * 32;
            a0 = *(const float4*)(Ap2);
            a1 = *(const float4*)(Ap2 + 4);
            w0 = *(const float4*)(Wp2);
            w1 = *(const float4*)(Wp2 + 4);
        }

        bf16x8 af0 = *(const bf16x8*)&As[wr + l15][kof];
        bf16x8 af1 = *(const bf16x8*)&As[wr + 16 + l15][kof];
        bf16x8 bf0 = *(const bf16x8*)&Ws[wc + l15][kof];
        bf16x8 bf1 = *(const bf16x8*)&Ws[wc + 16 + l15][kof];

        acc00 = __builtin_amdgcn_mfma_f32_16x16x32_bf16(af0, bf0, acc00, 0, 0, 0);
        acc01 = __builtin_amdgcn_mfma_f32_16x16x32_bf16(af0, bf1, acc01, 0, 0, 0);
        acc10 = __builtin_amdgcn_mfma_f32_16x16x32_bf16(af1, bf0, acc10, 0, 0, 0);
        acc11 = __builtin_amdgcn_mfma_f32_16x16x32_bf16(af1, bf1, acc11, 0, 0, 0);
        __syncthreads();
    }

    const int crow = brow + wr + ((lane >> 4) << 2);
    const int ccol = bcol + wc + l15;
    const float bias0 = bh[ccol];
    const float bias1 = bh[ccol + 16];
    #pragma unroll
    for (int r = 0; r < 4; ++r) {
        hatt[(size_t)(crow + r) * NA + ccol]           = acc00[r] + bias0;
        hatt[(size_t)(crow + r) * NA + ccol + 16]      = acc01[r] + bias1;
        hatt[(size_t)(crow + 16 + r) * NA + ccol]      = acc10[r] + bias0;
        hatt[(size_t)(crow + 16 + r) * NA + ccol + 16] = acc11[r] + bias1;
    }
}

// ---------------------------------------------------------------------------
// Kernel 2: partial scores. Block j: b = j>>1, a-half = j&1 (a in [ah,ah+512)).
// Wave wid handles l = wid, wid+4, ... (49 rows). Per row: 2 float4 loads,
// relu-dot over 512 elems, 6-shfl reduce, lane0 writes spart[(b*196+l)*2+ah].
// No barriers, 2048 blocks -> 32 waves/CU.
// ---------------------------------------------------------------------------
__global__ __launch_bounds__(256) void scores_kernel(
    const float* __restrict__ fproj,   // [NB, NL, NA]
    const float* __restrict__ hatt,    // [NB, NA] (ws)
    const float* __restrict__ wout,    // [NA]
    float* __restrict__ spart)         // [NB, NL, 2] (ws)
{
    const int t    = threadIdx.x;
    const int lane = t & 63;
    const int wid  = t >> 6;
    const int j    = blockIdx.x;
    const int b    = j >> 1;
    const int ahb  = (j & 1) << 9;     // 0 or 512

    const float* hrow = hatt + (size_t)b * NA + ahb + lane * 4;
    const float* wrow = wout + ahb + lane * 4;
    float4 h0 = *(const float4*)(hrow);
    float4 h1 = *(const float4*)(hrow + 256);
    float4 wv0 = *(const float4*)(wrow);
    float4 wv1 = *(const float4*)(wrow + 256);
    float hr[8] = {h0.x, h0.y, h0.z, h0.w, h1.x, h1.y, h1.z, h1.w};
    float wr[8] = {wv0.x, wv0.y, wv0.z, wv0.w, wv1.x, wv1.y, wv1.z, wv1.w};

    const float* fpb = fproj + (size_t)b * NL * NA + ahb + lane * 4;

    #pragma unroll 4
    for (int l = wid; l < NL; l += 4) {
        const float* row = fpb + (size_t)l * NA;
        float4 f0 = *(const float4*)(row);
        float4 f1 = *(const float4*)(row + 256);
        float fr[8] = {f0.x, f0.y, f0.z, f0.w, f1.x, f1.y, f1.z, f1.w};
        float p = 0.f;
        #pragma unroll
        for (int e = 0; e < 8; ++e)
            p = fmaf(fmaxf(hr[e] + fr[e], 0.f), wr[e], p);
        #pragma unroll
        for (int m = 32; m; m >>= 1) p += __shfl_xor(p, m, 64);
        if (lane == 0) spart[((size_t)b * NL + l) * 2 + (j & 1)] = p;
    }
}

// ---------------------------------------------------------------------------
// Kernel 3: softmax + partial context. Block j: b = j>>1, l-half = j&1.
// Combines score halves, computes softmax over 196 (redundantly in both
// blocks of a pair), streams its 98 feature rows into cpart[lh][b][:].
// ---------------------------------------------------------------------------
__global__ __launch_bounds__(256) void ctx_kernel(
    const float* __restrict__ features,  // [NB, NL, NA]
    const float* __restrict__ spart,     // [NB, NL, 2] (ws)
    float* __restrict__ cpart)           // [2, NB, NA] (ws)
{
    __shared__ float s_alpha[NL];
    __shared__ float s_red[4];

    const int t    = threadIdx.x;
    const int lane = t & 63;
    const int wid  = t >> 6;
    const int j    = blockIdx.x;
    const int b    = j >> 1;
    const int lh   = j & 1;

    float sv = -INFINITY;
    if (t < NL) {
        const float* sp = spart + ((size_t)b * NL + t) * 2;
        sv = sp[0] + sp[1];
    }
    float mx = sv;
    #pragma unroll
    for (int m = 32; m; m >>= 1) mx = fmaxf(mx, __shfl_xor(mx, m, 64));
    if (lane == 0) s_red[wid] = mx;
    __syncthreads();
    mx = fmaxf(fmaxf(s_red[0], s_red[1]), fmaxf(s_red[2], s_red[3]));
    float e = (t < NL) ? __expf(sv - mx) : 0.f;
    float sm = e;
    #pragma unroll
    for (int m = 32; m; m >>= 1) sm += __shfl_xor(sm, m, 64);
    __syncthreads();
    if (lane == 0) s_red[wid] = sm;
    __syncthreads();
    sm = s_red[0] + s_red[1] + s_red[2] + s_red[3];
    if (t < NL) s_alpha[t] = e / sm;
    __syncthreads();

    const int l0 = lh * 98;
    const float* fb = features + ((size_t)b * NL + l0) * NA + t * 4;
    float4 acc = {0.f, 0.f, 0.f, 0.f};
    #pragma unroll 7
    for (int i = 0; i < 98; ++i) {
        const float al = s_alpha[l0 + i];
        float4 f = *(const float4*)(fb + (size_t)i * NA);
        acc.x = fmaf(al, f.x, acc.x);
        acc.y = fmaf(al, f.y, acc.y);
        acc.z = fmaf(al, f.z, acc.z);
        acc.w = fmaf(al, f.w, acc.w);
    }
    *(float4*)(cpart + ((size_t)lh * NB + b) * NA + t * 4) = acc;
}

// ---------------------------------------------------------------------------
// Kernel 4: out[b][d] = cpart[0][b][d] + cpart[1][b][d]
// ---------------------------------------------------------------------------
__global__ __launch_bounds__(256) void add_kernel(
    const float* __restrict__ cpart, float* __restrict__ out)
{
    const int b = blockIdx.x;
    const int d = threadIdx.x * 4;
    float4 c0 = *(const float4*)(cpart + (size_t)b * NA + d);
    float4 c1 = *(const float4*)(cpart + (size_t)(NB + b) * NA + d);
    float4 o = {c0.x + c1.x, c0.y + c1.y, c0.z + c1.z, c0.w + c1.w};
    *(float4*)(out + (size_t)b * NA + d) = o;
}

extern "C" void kernel_launch(void* const* d_in, const int* in_sizes, int n_in,
                              void* d_out, int out_size, void* d_ws, size_t ws_size,
                              hipStream_t stream) {
    const float* features = (const float*)d_in[0];  // [1024,196,1024]
    const float* fproj    = (const float*)d_in[1];  // [1024,196,1024]
    const float* hp       = (const float*)d_in[2];  // [1024,1024]
    const float* Wh       = (const float*)d_in[3];  // [1024,1024]
    const float* bh       = (const float*)d_in[4];  // [1024]
    const float* wout     = (const float*)d_in[5];  // [1024]
    // d_in[6] = b_out: softmax(s + c) == softmax(s), provably unused.
    float* out  = (float*)d_out;                    // [1024,1024]
    float* wsf  = (float*)d_ws;
    float* hatt  = wsf + HATT_OFF;
    float* spart = wsf + SPART_OFF;
    float* cpart = wsf + CPART_OFF;

    hatt_gemm_mfma<<<dim3(16, 16), 256, 0, stream>>>(hp, Wh, bh, hatt);
    scores_kernel<<<2 * NB, 256, 0, stream>>>(fproj, hatt, wout, spart);
    ctx_kernel<<<2 * NB, 256, 0, stream>>>(features, spart, cpart);
    add_kernel<<<NB, 256, 0, stream>>>(cpart, out);
}

// Round 5
// 268.413 us; speedup vs baseline: 1.2408x; 1.2408x over previous
//
#include <hip/hip_runtime.h>
#include <math.h>

#define NB 1024
#define NL 196
#define NA 1024
#define NH 1024

typedef __attribute__((ext_vector_type(8))) short bf16x8;
typedef __attribute__((ext_vector_type(4))) float f32x4;

// f32 -> bf16 round-to-nearest-even, returned as raw bits
__device__ inline short f2bf(float x) {
    unsigned int u = __float_as_uint(x);
    u += 0x7FFFu + ((u >> 16) & 1u);
    return (short)(u >> 16);
}

// ---------------------------------------------------------------------------
// Kernel 1: h_att[b,a] = sum_k h_prev[b,k] * W_h[a,k] + b_h[a]   (bf16 MFMA)
// 64x64 tile, BK=32, LDS pitch 40 shorts. Writes to ws.
// ---------------------------------------------------------------------------
__global__ __launch_bounds__(256) void hatt_gemm_mfma(
    const float* __restrict__ hp,   // [NB, NH]
    const float* __restrict__ Wh,   // [NA, NH]
    const float* __restrict__ bh,   // [NA]
    float* __restrict__ hatt)       // [NB, NA] (ws)
{
    __shared__ short As[64][40];
    __shared__ short Ws[64][40];

    const int t   = threadIdx.x;
    const int row = t >> 2;          // 0..63
    const int c8  = (t & 3) << 3;    // 0,8,16,24
    const int brow = blockIdx.y << 6;
    const int bcol = blockIdx.x << 6;

    const float* Ap = hp + (size_t)(brow + row) * NH + c8;
    const float* Wp = Wh + (size_t)(bcol + row) * NH + c8;

    float4 a0 = *(const float4*)(Ap);
    float4 a1 = *(const float4*)(Ap + 4);
    float4 w0 = *(const float4*)(Wp);
    float4 w1 = *(const float4*)(Wp + 4);

    const int lane = t & 63;
    const int wid  = t >> 6;
    const int wr   = (wid >> 1) << 5;
    const int wc   = (wid & 1) << 5;
    const int l15  = lane & 15;
    const int kof  = (lane >> 4) << 3;

    f32x4 acc00 = {}, acc01 = {}, acc10 = {}, acc11 = {};

    for (int kt = 0; kt < NH / 32; ++kt) {
        bf16x8 pa, pb;
        pa[0]=f2bf(a0.x); pa[1]=f2bf(a0.y); pa[2]=f2bf(a0.z); pa[3]=f2bf(a0.w);
        pa[4]=f2bf(a1.x); pa[5]=f2bf(a1.y); pa[6]=f2bf(a1.z); pa[7]=f2bf(a1.w);
        pb[0]=f2bf(w0.x); pb[1]=f2bf(w0.y); pb[2]=f2bf(w0.z); pb[3]=f2bf(w0.w);
        pb[4]=f2bf(w1.x); pb[5]=f2bf(w1.y); pb[6]=f2bf(w1.z); pb[7]=f2bf(w1.w);
        *(bf16x8*)&As[row][c8] = pa;
        *(bf16x8*)&Ws[row][c8] = pb;
        __syncthreads();

        if (kt + 1 < NH / 32) {
            const float* Ap2 = Ap + (kt + 1) * 32;
            const float* Wp2 = Wp + (kt + 1) * 32;
            a0 = *(const float4*)(Ap2);
            a1 = *(const float4*)(Ap2 + 4);
            w0 = *(const float4*)(Wp2);
            w1 = *(const float4*)(Wp2 + 4);
        }

        bf16x8 af0 = *(const bf16x8*)&As[wr + l15][kof];
        bf16x8 af1 = *(const bf16x8*)&As[wr + 16 + l15][kof];
        bf16x8 bf0 = *(const bf16x8*)&Ws[wc + l15][kof];
        bf16x8 bf1 = *(const bf16x8*)&Ws[wc + 16 + l15][kof];

        acc00 = __builtin_amdgcn_mfma_f32_16x16x32_bf16(af0, bf0, acc00, 0, 0, 0);
        acc01 = __builtin_amdgcn_mfma_f32_16x16x32_bf16(af0, bf1, acc01, 0, 0, 0);
        acc10 = __builtin_amdgcn_mfma_f32_16x16x32_bf16(af1, bf0, acc10, 0, 0, 0);
        acc11 = __builtin_amdgcn_mfma_f32_16x16x32_bf16(af1, bf1, acc11, 0, 0, 0);
        __syncthreads();
    }

    const int crow = brow + wr + ((lane >> 4) << 2);
    const int ccol = bcol + wc + l15;
    const float bias0 = bh[ccol];
    const float bias1 = bh[ccol + 16];
    #pragma unroll
    for (int r = 0; r < 4; ++r) {
        hatt[(size_t)(crow + r) * NA + ccol]           = acc00[r] + bias0;
        hatt[(size_t)(crow + r) * NA + ccol + 16]      = acc01[r] + bias1;
        hatt[(size_t)(crow + 16 + r) * NA + ccol]      = acc10[r] + bias0;
        hatt[(size_t)(crow + 16 + r) * NA + ccol + 16] = acc11[r] + bias1;
    }
}

// ---------------------------------------------------------------------------
// Kernel 2 (fused): one block per batch row b.
//  Phase A: wave w scores rows l = w, w+4, ... ; ONE block barrier; per-wave
//  redundant softmax into a private alpha copy; 4 feature rows prefetched
//  into regs before softmax; Phase B context accumulate.
//  All streaming loads nontemporal (read-once data, don't pollute L2/L3).
// ---------------------------------------------------------------------------
__global__ __launch_bounds__(256, 4) void attn_main_kernel(
    const float* __restrict__ features,  // [NB, NL, NA]
    const float* __restrict__ fproj,     // [NB, NL, NA]
    const float* __restrict__ hatt,      // [NB, NA] (ws)
    const float* __restrict__ wout,      // [NA]
    float* __restrict__ out)             // [NB, NA]
{
    __shared__ float s_score[NL];
    __shared__ float s_alpha[4][NL];     // per-wave private copy

    const int t    = threadIdx.x;
    const int lane = t & 63;
    const int wid  = t >> 6;
    const int b    = blockIdx.x;

    // per-lane h_att / w_out fragments (a = lane*4 + c*256)
    const float* hrow = hatt + (size_t)b * NA;
    float hreg[4][4], wreg[4][4];
    #pragma unroll
    for (int c = 0; c < 4; ++c) {
        f32x4 h4 = *(const f32x4*)(hrow + c * 256 + lane * 4);
        f32x4 w4 = *(const f32x4*)(wout + c * 256 + lane * 4);
        hreg[c][0] = h4[0]; hreg[c][1] = h4[1]; hreg[c][2] = h4[2]; hreg[c][3] = h4[3];
        wreg[c][0] = w4[0]; wreg[c][1] = w4[1]; wreg[c][2] = w4[2]; wreg[c][3] = w4[3];
    }

    // ---- Phase A: scores (nt streaming loads) ----
    const float* fpb = fproj + (size_t)b * NL * NA;
    #pragma unroll 2
    for (int l = wid; l < NL; l += 4) {
        const float* row = fpb + (size_t)l * NA + lane * 4;
        f32x4 f[4];
        #pragma unroll
        for (int c = 0; c < 4; ++c)
            f[c] = __builtin_nontemporal_load((const f32x4*)(row + c * 256));
        float p = 0.f;
        #pragma unroll
        for (int c = 0; c < 4; ++c) {
            #pragma unroll
            for (int j = 0; j < 4; ++j)
                p = fmaf(fmaxf(hreg[c][j] + f[c][j], 0.f), wreg[c][j], p);
        }
        #pragma unroll
        for (int m = 32; m; m >>= 1) p += __shfl_xor(p, m, 64);
        if (lane == 0) s_score[l] = p;
    }
    __syncthreads();   // the only block-wide barrier

    // ---- prefetch first 4 feature rows (keeps VMEM busy through softmax) ----
    const float* fb = features + (size_t)b * NL * NA + t * 4;
    f32x4 pf0 = __builtin_nontemporal_load((const f32x4*)(fb + 0 * NA));
    f32x4 pf1 = __builtin_nontemporal_load((const f32x4*)(fb + 1 * NA));
    f32x4 pf2 = __builtin_nontemporal_load((const f32x4*)(fb + 2 * NA));
    f32x4 pf3 = __builtin_nontemporal_load((const f32x4*)(fb + 3 * NA));

    // ---- per-wave redundant softmax (no extra barriers) ----
    float v0 = s_score[lane];
    float v1 = s_score[64 + lane];
    float v2 = s_score[128 + lane];
    float v3 = (lane < 4) ? s_score[192 + lane] : -INFINITY;
    float mx = fmaxf(fmaxf(v0, v1), fmaxf(v2, v3));
    #pragma unroll
    for (int m = 32; m; m >>= 1) mx = fmaxf(mx, __shfl_xor(mx, m, 64));
    float e0 = __expf(v0 - mx);
    float e1 = __expf(v1 - mx);
    float e2 = __expf(v2 - mx);
    float e3 = (lane < 4) ? __expf(v3 - mx) : 0.f;
    float sm = e0 + e1 + e2 + e3;
    #pragma unroll
    for (int m = 32; m; m >>= 1) sm += __shfl_xor(sm, m, 64);
    const float inv = 1.0f / sm;
    float* aw = s_alpha[wid];
    aw[lane]       = e0 * inv;
    aw[64 + lane]  = e1 * inv;
    aw[128 + lane] = e2 * inv;
    if (lane < 4) aw[192 + lane] = e3 * inv;
    // wave reads only its own writes below -> in-wave lgkmcnt ordering suffices

    // ---- Phase B: context ----
    f32x4 acc = {0.f, 0.f, 0.f, 0.f};
    {
        float a0 = aw[0], a1 = aw[1], a2 = aw[2], a3 = aw[3];
        #pragma unroll
        for (int j = 0; j < 4; ++j)
            acc[j] = fmaf(a0, pf0[j], fmaf(a1, pf1[j], fmaf(a2, pf2[j], a3 * pf3[j])));
    }
    #pragma unroll 8
    for (int l = 4; l < NL; ++l) {
        const float al = aw[l];
        f32x4 f = __builtin_nontemporal_load((const f32x4*)(fb + (size_t)l * NA));
        #pragma unroll
        for (int j = 0; j < 4; ++j)
            acc[j] = fmaf(al, f[j], acc[j]);
    }
    *(f32x4*)(out + (size_t)b * NA + t * 4) = acc;
}

extern "C" void kernel_launch(void* const* d_in, const int* in_sizes, int n_in,
                              void* d_out, int out_size, void* d_ws, size_t ws_size,
                              hipStream_t stream) {
    const float* features = (const float*)d_in[0];  // [1024,196,1024]
    const float* fproj    = (const float*)d_in[1];  // [1024,196,1024]
    const float* hp       = (const float*)d_in[2];  // [1024,1024]
    const float* Wh       = (const float*)d_in[3];  // [1024,1024]
    const float* bh       = (const float*)d_in[4];  // [1024]
    const float* wout     = (const float*)d_in[5];  // [1024]
    // d_in[6] = b_out: softmax(s + c) == softmax(s), provably unused.
    float* out  = (float*)d_out;                    // [1024,1024]
    float* hatt = (float*)d_ws;                     // [1024,1024] scratch

    hatt_gemm_mfma<<<dim3(16, 16), 256, 0, stream>>>(hp, Wh, bh, hatt);
    attn_main_kernel<<<NB, 256, 0, stream>>>(features, fproj, hatt, wout, out);
}